// Round 19
// baseline (420.598 us; speedup 1.0000x reference)
//
#include <hip/hip_runtime.h>
#include <hip/hip_bf16.h>

#define C_ 256
#define L_ 16384
#define CL_ (C_*L_)

typedef unsigned int u32;
typedef unsigned short u16;
typedef __bf16 bf16_t;
typedef bf16_t bf16x8 __attribute__((ext_vector_type(8)));
typedef float f32x4 __attribute__((ext_vector_type(4)));

__device__ __forceinline__ float bf2f(u16 v){ return __builtin_bit_cast(float, ((u32)v)<<16); }
__device__ __forceinline__ u16 f2bf(float f){
  bf16_t h = (bf16_t)f;
  return __builtin_bit_cast(u16, h);
}
__device__ __forceinline__ u32 pack2(float a, float b){
  return (u32)f2bf(a) | ((u32)f2bf(b)<<16);
}

#define AST 528    // A-tile stride (64 x 264 u16), affine + conflict-free
#define HST 272    // BufH stride (64 x 136 u16)
#define CST 136    // c-major stride (256 x 68 u16)
#define OST 68     // OutF stride (floats)

// ---------------- weight PACK kernel ----------------
__global__ void wpack_kernel(const float* __restrict__ qkvw, const float* __restrict__ projw,
                             const float* __restrict__ f1w, const float* __restrict__ f2w,
                             u16* __restrict__ pq, u16* __restrict__ pp,
                             u16* __restrict__ p1, u16* __restrict__ p2)
{
  int bid = blockIdx.x, tid = threadIdx.x;
  const float* src; u16* dst; int stride, n, k;
  if (bid < 96){
    int f = bid*256 + tid;
    int l = f & 63, nt = (f>>6) & 15, kk = f>>10;
    int s = kk>>3, ks = kk&7;
    stride = 768; src = qkvw;
    n = s*256 + nt*16 + (l&15);
    k = ks*32 + ((l>>4)<<3);
    dst = pq + (size_t)s*65536 + ((size_t)(ks*16 + nt)*64 + l)*8;
  } else if (bid < 128){
    int f = (bid-96)*256 + tid;
    int l = f & 63, nt = (f>>6) & 15, ks = f>>10;
    stride = 256; src = projw;
    n = nt*16 + (l&15);
    k = ks*32 + ((l>>4)<<3);
    dst = pp + ((size_t)(ks*16 + nt)*64 + l)*8;
  } else if (bid < 256){
    int f = (bid-128)*256 + tid;
    int l = f & 63, nt = (f>>6) & 15, kk = f>>10;
    int c2 = kk>>3, ks = kk&7;
    stride = 1024; src = f1w;
    n = c2*256 + nt*16 + (l&15);
    k = ks*32 + ((l>>4)<<3);
    dst = p1 + (size_t)c2*65536 + ((size_t)(ks*16 + nt)*64 + l)*8;
  } else {
    int f = (bid-256)*256 + tid;
    int l = f & 63, nt = (f>>6) & 15, ks = f>>10;
    stride = 256; src = f2w;
    n = nt*16 + (l&15);
    k = ks*32 + ((l>>4)<<3);
    dst = p2 + ((size_t)(ks*16 + nt)*64 + l)*8;
  }
  u16 v[8];
  #pragma unroll
  for (int j = 0; j < 8; ++j) v[j] = f2bf(src[(size_t)(k+j)*stride + n]);
  uint4 o;
  o.x = (u32)v[0] | ((u32)v[1]<<16);
  o.y = (u32)v[2] | ((u32)v[3]<<16);
  o.z = (u32)v[4] | ((u32)v[5]<<16);
  o.w = (u32)v[6] | ((u32)v[7]<<16);
  *(uint4*)dst = o;
}

// ---------------- padded-layout GEMM helpers ----------------
__device__ __forceinline__ void gemmP(const u16* Abase, const u16* __restrict__ pk,
                                      int l, int ntb, f32x4 acc[4][2])
{
  const char* ab = (const char*)Abase + (l&15)*AST + ((l>>4)<<4);
  const u16* bp = pk + ((size_t)ntb*64 + l)*8;
  #pragma unroll
  for (int ks = 0; ks < 8; ++ks){
    const u16* bk = bp + (size_t)ks*8192;
    bf16x8 b0 = *(const bf16x8*)(bk);
    bf16x8 b1 = *(const bf16x8*)(bk + 512);
    bf16x8 a[4];
    #pragma unroll
    for (int m = 0; m < 4; ++m)
      a[m] = *(const bf16x8*)(ab + m*(16*AST) + ks*64);
    #pragma unroll
    for (int m = 0; m < 4; ++m){
      acc[m][0] = __builtin_amdgcn_mfma_f32_16x16x32_bf16(a[m], b0, acc[m][0], 0, 0, 0);
      acc[m][1] = __builtin_amdgcn_mfma_f32_16x16x32_bf16(a[m], b1, acc[m][1], 0, 0, 0);
    }
  }
}
#define ZERO_ACC(A) { _Pragma("unroll") for (int m_ = 0; m_ < 4; ++m_){ A[m_][0] = (f32x4){0,0,0,0}; A[m_][1] = (f32x4){0,0,0,0}; } }

// merged Q/K/V GEMM: A loaded once, 24 MFMAs per K-step
__device__ __forceinline__ void gemmP3(const u16* Abase, const u16* __restrict__ pkq,
                                       int l, int ntb,
                                       f32x4 aq[4][2], f32x4 ak[4][2], f32x4 av[4][2])
{
  const char* ab = (const char*)Abase + (l&15)*AST + ((l>>4)<<4);
  const u16* bq = pkq + ((size_t)ntb*64 + l)*8;
  #pragma unroll
  for (int ks = 0; ks < 8; ++ks){
    const u16* bkq = bq + (size_t)ks*8192;
    bf16x8 q0 = *(const bf16x8*)(bkq);
    bf16x8 q1 = *(const bf16x8*)(bkq + 512);
    bf16x8 k0 = *(const bf16x8*)(bkq + 65536);
    bf16x8 k1 = *(const bf16x8*)(bkq + 65536 + 512);
    bf16x8 v0 = *(const bf16x8*)(bkq + 131072);
    bf16x8 v1 = *(const bf16x8*)(bkq + 131072 + 512);
    bf16x8 a[4];
    #pragma unroll
    for (int m = 0; m < 4; ++m)
      a[m] = *(const bf16x8*)(ab + m*(16*AST) + ks*64);
    #pragma unroll
    for (int m = 0; m < 4; ++m){
      aq[m][0] = __builtin_amdgcn_mfma_f32_16x16x32_bf16(a[m], q0, aq[m][0], 0, 0, 0);
      aq[m][1] = __builtin_amdgcn_mfma_f32_16x16x32_bf16(a[m], q1, aq[m][1], 0, 0, 0);
      ak[m][0] = __builtin_amdgcn_mfma_f32_16x16x32_bf16(a[m], k0, ak[m][0], 0, 0, 0);
      ak[m][1] = __builtin_amdgcn_mfma_f32_16x16x32_bf16(a[m], k1, ak[m][1], 0, 0, 0);
      av[m][0] = __builtin_amdgcn_mfma_f32_16x16x32_bf16(a[m], v0, av[m][0], 0, 0, 0);
      av[m][1] = __builtin_amdgcn_mfma_f32_16x16x32_bf16(a[m], v1, av[m][1], 0, 0, 0);
    }
  }
}

// old-layout GEMM for fallback kernel
__device__ __forceinline__ void gemmF(const u16* Abase, const u16* __restrict__ pk,
                                      int l, int ntb, f32x4 acc[4][2])
{
  #pragma unroll
  for (int ks = 0; ks < 8; ++ks){
    bf16x8 b0 = *(const bf16x8*)(pk + ((size_t)(ks*16 + ntb    )*64 + l)*8);
    bf16x8 b1 = *(const bf16x8*)(pk + ((size_t)(ks*16 + ntb + 1)*64 + l)*8);
    int k0 = ks*32;
    bf16x8 a[4];
    #pragma unroll
    for (int m = 0; m < 4; ++m){
      int t = m*16 + (l & 15);
      int off = t*512 + ((2*(k0 + ((l>>4)<<3))) ^ ((t&7)<<4));
      a[m] = *(const bf16x8*)((const char*)Abase + off);
    }
    #pragma unroll
    for (int m = 0; m < 4; ++m){
      acc[m][0] = __builtin_amdgcn_mfma_f32_16x16x32_bf16(a[m], b0, acc[m][0], 0, 0, 0);
      acc[m][1] = __builtin_amdgcn_mfma_f32_16x16x32_bf16(a[m], b1, acc[m][1], 0, 0, 0);
    }
  }
}

// ================= kernel 1: LN1 + attention (merged QKV, 3-buffer phase-compressed) =================
// LDS layout (fixed r18 overflow): Buf1 [0,33792) | BufK [33792,67584) |
// BufQ [67584,102400) (needs 34816 for c-major xt1) | redF/statsF at 102400 (4608 B)
__launch_bounds__(512, 2)
__global__ void swin_attn_kernel(const float* __restrict__ x,
                                 const float* __restrict__ n1w, const float* __restrict__ n1b,
                                 const u16* __restrict__ pkq, const u16* __restrict__ pkp,
                                 const float* __restrict__ projb,
                                 u16* __restrict__ xt1g, float* __restrict__ statsg)
{
  __shared__ char smem[107008];            // 104.5 KiB, 1 block/CU
  u16* Buf1 = (u16*)smem;                  // [64][264] A-ln1 -> raw x
  char* BufK = smem + 33792;               // [64][264] K -> O
  char* BufQ = smem + 67584;               // [64][264] Q -> V -> [256][68] c-major xt1 (34816 B)
  float* redF = (float*)(smem + 102400);   // [2][8][64] partials
  float* statsF = redF + 1024;             // [64][2]

  const int tid = threadIdx.x;
  const int w = tid >> 6;
  const int l = tid & 63;
  const int bb = blockIdx.x >> 8;
  const int blkl = blockIdx.x & 255;
  const int l0 = blkl*64 + 4;
  const float* xb = x + (size_t)bb*CL_;
  const int ntb = w*2;

  // ---- LN1 ----
  const int q4 = tid & 15, cg = tid >> 4;
  int lq = l0 + 4*q4; if (lq >= L_) lq -= L_;
  u32 praw[4][4];
  {
    float4 xr[8];
    float s1[4] = {0.f,0.f,0.f,0.f};
    float s2[4] = {0.f,0.f,0.f,0.f};
    #pragma unroll
    for (int ci = 0; ci < 8; ++ci){
      int c = cg*8 + ci;
      float4 d = *(const float4*)(xb + (size_t)c*L_ + lq);
      xr[ci] = d;
      s1[0]+=d.x; s2[0]+=d.x*d.x;  s1[1]+=d.y; s2[1]+=d.y*d.y;
      s1[2]+=d.z; s2[2]+=d.z*d.z;  s1[3]+=d.w; s2[3]+=d.w*d.w;
    }
    #pragma unroll
    for (int off = 16; off < 64; off <<= 1){
      #pragma unroll
      for (int jj = 0; jj < 4; ++jj){
        s1[jj] += __shfl_xor(s1[jj], off);
        s2[jj] += __shfl_xor(s2[jj], off);
      }
    }
    if (l < 16){
      #pragma unroll
      for (int jj = 0; jj < 4; ++jj){
        redF[w*64 + 4*l + jj] = s1[jj];
        redF[512 + w*64 + 4*l + jj] = s2[jj];
      }
    }
    __syncthreads();
    if (tid < 64){
      float a = 0.f, b2 = 0.f;
      #pragma unroll
      for (int ww = 0; ww < 8; ++ww){ a += redF[ww*64 + tid]; b2 += redF[512 + ww*64 + tid]; }
      float mu = a * (1.f/256.f);
      float var = fmaxf(b2 * (1.f/256.f) - mu*mu, 0.f);
      statsF[2*tid] = mu;
      statsF[2*tid+1] = rsqrtf(var + 1e-5f);
    }
    __syncthreads();
    #pragma unroll
    for (int jj = 0; jj < 4; ++jj){
      int t = 4*q4 + jj;
      float mu = statsF[2*t], rs = statsF[2*t+1];
      u32 aw[4];
      #pragma unroll
      for (int cp = 0; cp < 4; ++cp){
        int c0c = cg*8 + 2*cp;
        float v0 = ((const float*)&xr[2*cp])[jj];
        float v1 = ((const float*)&xr[2*cp+1])[jj];
        aw[cp] = pack2((v0-mu)*rs*n1w[c0c] + n1b[c0c], (v1-mu)*rs*n1w[c0c+1] + n1b[c0c+1]);
        praw[jj][cp] = pack2(v0, v1);
      }
      *(uint4*)((char*)Buf1 + t*AST + cg*16) = make_uint4(aw[0],aw[1],aw[2],aw[3]);
    }
  }
  __syncthreads();                          // A: A-ln1 ready

  // ---- merged Q/K/V GEMM ----
  f32x4 aq[4][2], ak[4][2], av[4][2];
  ZERO_ACC(aq); ZERO_ACC(ak); ZERO_ACC(av);
  gemmP3(Buf1, pkq, l, ntb, aq, ak, av);

  // ---- retire K -> BufK and Q -> BufQ (no intervening barrier) ----
  #pragma unroll
  for (int m = 0; m < 4; ++m)
    #pragma unroll
    for (int n2 = 0; n2 < 2; ++n2)
      #pragma unroll
      for (int jj = 0; jj < 4; ++jj){
        int t = m*16 + ((l>>4)<<2) + jj;
        int c = (w<<5) + (n2<<4) + (l&15);
        *(u16*)(BufK + t*AST + 2*c) = f2bf(ak[m][n2][jj]);
        *(u16*)(BufQ + t*AST + 2*c) = f2bf(aq[m][n2][jj]);
      }
  __syncthreads();                          // B: K,Q ready

  // ---- read kr + qf in ONE phase ----
  const int hh = (tid >> 3) & 7, rr = tid & 7;
  const int tq = w*8 + rr;
  u32 kr[16];
  float qf[32];
  #pragma unroll
  for (int g = 0; g < 4; ++g){
    uint4 dk = *(const uint4*)(BufK + tq*AST + hh*64 + 16*g);
    kr[g*4+0] = dk.x; kr[g*4+1] = dk.y; kr[g*4+2] = dk.z; kr[g*4+3] = dk.w;
    uint4 dq = *(const uint4*)(BufQ + tq*AST + hh*64 + 16*g);
    qf[g*8+0] = bf2f((u16)dq.x); qf[g*8+1] = bf2f((u16)(dq.x>>16));
    qf[g*8+2] = bf2f((u16)dq.y); qf[g*8+3] = bf2f((u16)(dq.y>>16));
    qf[g*8+4] = bf2f((u16)dq.z); qf[g*8+5] = bf2f((u16)(dq.z>>16));
    qf[g*8+6] = bf2f((u16)dq.w); qf[g*8+7] = bf2f((u16)(dq.w>>16));
  }
  __syncthreads();                          // C: all Q reads done

  // ---- retire V -> BufQ; dump praw -> Buf1; softmax (VALU overlaps LDS writes) ----
  #pragma unroll
  for (int m = 0; m < 4; ++m)
    #pragma unroll
    for (int n2 = 0; n2 < 2; ++n2)
      #pragma unroll
      for (int jj = 0; jj < 4; ++jj){
        int t = m*16 + ((l>>4)<<2) + jj;
        int c = (w<<5) + (n2<<4) + (l&15);
        *(u16*)(BufQ + t*AST + 2*c) = f2bf(av[m][n2][jj]);
      }
  #pragma unroll
  for (int jj = 0; jj < 4; ++jj){
    int t = 4*q4 + jj;
    *(uint4*)((char*)Buf1 + t*AST + cg*16) =
        make_uint4(praw[jj][0], praw[jj][1], praw[jj][2], praw[jj][3]);
  }
  float pr[8];
  {
    float s[8];
    #pragma unroll
    for (int j = 0; j < 8; ++j){
      float dot = 0.f;
      #pragma unroll
      for (int reg = 0; reg < 16; ++reg){
        u32 kj = (u32)__shfl((int)kr[reg], j, 8);
        dot += qf[2*reg]   * bf2f((u16)kj);
        dot += qf[2*reg+1] * bf2f((u16)(kj>>16));
      }
      s[j] = dot * 0.17677669529663687f;
    }
    float mx = s[0];
    #pragma unroll
    for (int j = 1; j < 8; ++j) mx = fmaxf(mx, s[j]);
    float sum = 0.f;
    #pragma unroll
    for (int j = 0; j < 8; ++j){ pr[j] = __expf(s[j]-mx); sum += pr[j]; }
    float inv = 1.0f / sum;
    #pragma unroll
    for (int j = 0; j < 8; ++j) pr[j] *= inv;
  }
  __syncthreads();                          // D: V ready

  // ---- PV: read V rows (own range), write O -> BufK (own range) ----
  {
    u32 vr[16];
    #pragma unroll
    for (int g = 0; g < 4; ++g){
      uint4 dv = *(const uint4*)(BufQ + tq*AST + hh*64 + 16*g);
      vr[g*4+0] = dv.x; vr[g*4+1] = dv.y; vr[g*4+2] = dv.z; vr[g*4+3] = dv.w;
    }
    float of[32];
    #pragma unroll
    for (int d = 0; d < 32; ++d) of[d] = 0.f;
    #pragma unroll
    for (int j = 0; j < 8; ++j){
      float pj = pr[j];
      #pragma unroll
      for (int reg = 0; reg < 16; ++reg){
        u32 vj = (u32)__shfl((int)vr[reg], j, 8);
        of[2*reg]   += pj*bf2f((u16)vj);
        of[2*reg+1] += pj*bf2f((u16)(vj>>16));
      }
    }
    #pragma unroll
    for (int g = 0; g < 4; ++g){
      uint4 o;
      o.x = pack2(of[g*8+0], of[g*8+1]);
      o.y = pack2(of[g*8+2], of[g*8+3]);
      o.z = pack2(of[g*8+4], of[g*8+5]);
      o.w = pack2(of[g*8+6], of[g*8+7]);
      *(uint4*)(BufK + tq*AST + hh*64 + 16*g) = o;
    }
  }
  __syncthreads();                          // E: O ready

  // ---- proj GEMM (A=BufK) + epi -> BufQ c-major xt1 ----
  {
    f32x4 acc[4][2]; ZERO_ACC(acc);
    gemmP((const u16*)BufK, pkp, l, ntb, acc);
    #pragma unroll
    for (int m = 0; m < 4; ++m)
      #pragma unroll
      for (int n2 = 0; n2 < 2; ++n2)
        #pragma unroll
        for (int jj = 0; jj < 4; ++jj){
          int t = m*16 + ((l>>4)<<2) + jj;
          int c = (w<<5) + (n2<<4) + (l&15);
          float rv = bf2f(*(const u16*)((char*)Buf1 + t*AST + 2*c));
          float v = acc[m][n2][jj] + projb[c] + rv;
          *(u16*)(BufQ + c*CST + 2*t) = f2bf(v);
        }
  }
  __syncthreads();                          // G: xt1 tile ready

  // ---- LN2 stats partials + xt1 global write ----
  {
    float a = 0.f, b2 = 0.f;
    #pragma unroll
    for (int ci = 0; ci < 32; ++ci){
      int c = (w<<5) + ci;
      float v = bf2f(*(const u16*)(BufQ + c*CST + 2*l));
      a += v; b2 += v*v;
    }
    redF[w*64 + l] = a;
    redF[512 + w*64 + l] = b2;
  }
  u16* xo = xt1g + (size_t)bb*CL_;
  #pragma unroll
  for (int ii = 0; ii < 8; ++ii){
    int id = tid + ii*512;
    int c = id >> 4, qd = id & 15;
    int lw = l0 + 4*qd; if (lw >= L_) lw -= L_;
    uint2 dd = *(const uint2*)(BufQ + c*CST + 8*qd);
    *(uint2*)(xo + (size_t)c*L_ + lw) = dd;
  }
  __syncthreads();                          // H
  if (tid < 64){
    float a = 0.f, b2 = 0.f;
    #pragma unroll
    for (int ww = 0; ww < 8; ++ww){ a += redF[ww*64 + tid]; b2 += redF[512 + ww*64 + tid]; }
    float mu = a * (1.f/256.f);
    float var = fmaxf(b2 * (1.f/256.f) - mu*mu, 0.f);
    float2 st; st.x = mu; st.y = rsqrtf(var + 1e-5f);
    *(float2*)(statsg + (size_t)(bb*16384 + blkl*64 + tid)*2) = st;
  }
}

// ================= kernel 2: LN2 + FF (pair-merged ff1, exp2 GELU) =================
__launch_bounds__(512, 4)
__global__ void swin_ff_kernel(const u16* __restrict__ xt1g, const float* __restrict__ statsg,
                               const float* __restrict__ n2w, const float* __restrict__ n2b,
                               const u16* __restrict__ pk1, const float* __restrict__ f1b,
                               const u16* __restrict__ pk2, const float* __restrict__ f2b,
                               float* __restrict__ out)
{
  __shared__ char smem[68608];
  u16* Buf1  = (u16*)smem;               // [64][264] A-ln2 (33792 B)
  char* BufH0 = smem + 33792;            // [64][136] H chunk j0 (17408 B)
  char* BufH1 = smem + 51200;            // [64][136] H chunk j1

  const int tid = threadIdx.x;
  const int w = tid >> 6;
  const int l = tid & 63;
  const int bb = blockIdx.x >> 8;
  const int blkl = blockIdx.x & 255;
  const int l0 = blkl*64 + 4;
  const u16* xi = xt1g + (size_t)bb*CL_;

  // ---- load xt1 (c-major) + LN2-normalize -> Buf1 ----
  const int q4 = tid & 15, cg = tid >> 4;
  int lq = l0 + 4*q4; if (lq >= L_) lq -= L_;
  {
    u32 xl[8][2];
    #pragma unroll
    for (int ci = 0; ci < 8; ++ci){
      int c = cg*8 + ci;
      uint2 dd = *(const uint2*)(xi + (size_t)c*L_ + lq);
      xl[ci][0] = dd.x; xl[ci][1] = dd.y;
    }
    #pragma unroll
    for (int jj = 0; jj < 4; ++jj){
      int t = 4*q4 + jj;
      float2 st = *(const float2*)(statsg + (size_t)(bb*16384 + blkl*64 + t)*2);
      float mu = st.x, rs = st.y;
      u32 aw[4];
      #pragma unroll
      for (int cp = 0; cp < 4; ++cp){
        int c0c = cg*8 + 2*cp;
        float v0 = bf2f((u16)(xl[2*cp  ][jj>>1] >> (16*(jj&1))));
        float v1 = bf2f((u16)(xl[2*cp+1][jj>>1] >> (16*(jj&1))));
        aw[cp] = pack2((v0-mu)*rs*n2w[c0c] + n2b[c0c], (v1-mu)*rs*n2w[c0c+1] + n2b[c0c+1]);
      }
      *(uint4*)((char*)Buf1 + t*AST + cg*16) = make_uint4(aw[0],aw[1],aw[2],aw[3]);
    }
  }
  __syncthreads();

  // ---- FF: 4 pair-steps; ff1 merged over chunk pair ----
  f32x4 acc2[4][2]; ZERO_ACC(acc2);
  const char* ab1 = (const char*)Buf1 + (l&15)*AST + ((l>>4)<<4);
  #pragma unroll 1
  for (int jp = 0; jp < 4; ++jp){
    f32x4 a1a[4], a1b[4];
    #pragma unroll
    for (int m = 0; m < 4; ++m){ a1a[m] = (f32x4){0,0,0,0}; a1b[m] = (f32x4){0,0,0,0}; }
    const u16* p1 = pk1 + (size_t)jp*65536;
    const u16* bpA = p1 + ((size_t)(w    )*64 + l)*8;
    const u16* bpB = p1 + ((size_t)(8 + w)*64 + l)*8;
    #pragma unroll
    for (int ks = 0; ks < 8; ++ks){
      bf16x8 bA = *(const bf16x8*)(bpA + (size_t)ks*8192);
      bf16x8 bB = *(const bf16x8*)(bpB + (size_t)ks*8192);
      #pragma unroll
      for (int m = 0; m < 4; ++m){
        bf16x8 a = *(const bf16x8*)(ab1 + m*(16*AST) + ks*64);
        a1a[m] = __builtin_amdgcn_mfma_f32_16x16x32_bf16(a, bA, a1a[m], 0, 0, 0);
        a1b[m] = __builtin_amdgcn_mfma_f32_16x16x32_bf16(a, bB, a1b[m], 0, 0, 0);
      }
    }
    // GELU both chunks -> BufH0 / BufH1 (sigmoid via native exp2)
    #pragma unroll
    for (int m = 0; m < 4; ++m)
      #pragma unroll
      for (int jj = 0; jj < 4; ++jj){
        int t = m*16 + ((l>>4)<<2) + jj;
        int cp_ = (w<<4) + (l&15);
        float xa = a1a[m][jj] + f1b[(2*jp)*128 + cp_];
        float ua = xa*(0.79788456f + 0.035677408f*xa*xa);
        *(u16*)(BufH0 + t*HST + 2*cp_) = f2bf(xa / (1.f + exp2f(-2.8853900817779268f*ua)));
        float xb = a1b[m][jj] + f1b[(2*jp+1)*128 + cp_];
        float ub = xb*(0.79788456f + 0.035677408f*xb*xb);
        *(u16*)(BufH1 + t*HST + 2*cp_) = f2bf(xb / (1.f + exp2f(-2.8853900817779268f*ub)));
      }
    __syncthreads();                 // H pair ready
    const u16* bp2 = pk2 + ((size_t)((8*jp)*16 + 2*w)*64 + l)*8;
    #pragma unroll
    for (int kk = 0; kk < 8; ++kk){
      const char* hb = (kk < 4) ? BufH0 : BufH1;
      const char* abh = hb + (l&15)*HST + ((l>>4)<<4);
      int ksl = kk & 3;
      const u16* bk = bp2 + (size_t)kk*8192;
      bf16x8 b0 = *(const bf16x8*)(bk);
      bf16x8 b1 = *(const bf16x8*)(bk + 512);
      bf16x8 a[4];
      #pragma unroll
      for (int m = 0; m < 4; ++m)
        a[m] = *(const bf16x8*)(abh + m*(16*HST) + ksl*64);
      #pragma unroll
      for (int m = 0; m < 4; ++m){
        acc2[m][0] = __builtin_amdgcn_mfma_f32_16x16x32_bf16(a[m], b0, acc2[m][0], 0, 0, 0);
        acc2[m][1] = __builtin_amdgcn_mfma_f32_16x16x32_bf16(a[m], b1, acc2[m][1], 0, 0, 0);
      }
    }
    __syncthreads();                 // ff2 reads done before next pair's GELU writes
  }

  // ---- epilogue: +f2b, fp32 stage (padded), +residual on store ----
  float* OutF = (float*)smem;            // [128 rows][68] fp32 padded
  float* ob = out + (size_t)bb*CL_;
  #pragma unroll
  for (int n2p = 0; n2p < 2; ++n2p){
    __syncthreads();
    #pragma unroll
    for (int m = 0; m < 4; ++m)
      #pragma unroll
      for (int jj = 0; jj < 4; ++jj){
        int t = m*16 + ((l>>4)<<2) + jj;
        int c = (w<<5) + (n2p<<4) + (l&15);
        int row = (w<<4) + (l&15);
        float v = acc2[m][n2p][jj] + f2b[c];
        OutF[row*OST + t] = v;
      }
    __syncthreads();
    #pragma unroll
    for (int ii = 0; ii < 4; ++ii){
      int id = tid + ii*512;
      int row = id >> 4, qd = id & 15;
      int cg_ = ((row>>4)<<5) + (n2p<<4) + (row&15);
      int lw = l0 + 4*qd; if (lw >= L_) lw -= L_;
      float4 vv = *(const float4*)(OutF + row*OST + 4*qd);
      uint2 rr2 = *(const uint2*)(xi + (size_t)cg_*L_ + lw);
      vv.x += bf2f((u16)rr2.x);  vv.y += bf2f((u16)(rr2.x>>16));
      vv.z += bf2f((u16)rr2.y);  vv.w += bf2f((u16)(rr2.y>>16));
      *(float4*)(ob + (size_t)cg_*L_ + lw) = vv;
    }
  }
}

// ================= fallback: fused kernel (old layout; used if ws too small) =================
__launch_bounds__(512, 2)
__global__ void swin_fused_kernel(const float* __restrict__ x,
                                  const float* __restrict__ n1w, const float* __restrict__ n1b,
                                  const float* __restrict__ n2w, const float* __restrict__ n2b,
                                  const u16* __restrict__ pkq, const u16* __restrict__ pkp,
                                  const float* __restrict__ projb,
                                  const u16* __restrict__ pk1, const float* __restrict__ f1b,
                                  const u16* __restrict__ pk2, const float* __restrict__ f2b,
                                  float* __restrict__ out)
{
  __shared__ u16 smem[35072];
  u16* Buf1 = smem;
  u16* Buf2 = smem + 16384;
  float* redF   = (float*)(smem + 32768);
  float* statsF = redF + 1024;

  const int tid = threadIdx.x;
  const int w = tid >> 6;
  const int l = tid & 63;
  const int bb = blockIdx.x >> 8;
  const int blkl = blockIdx.x & 255;
  const int l0 = blkl*64 + 4;
  const float* xb = x + (size_t)bb*CL_;
  const int ntb = w*2;

  const int q4 = tid & 15, cg = tid >> 4;
  int lq = l0 + 4*q4; if (lq >= L_) lq -= L_;
  float4 xr[8];
  float s1[4] = {0.f,0.f,0.f,0.f};
  float s2[4] = {0.f,0.f,0.f,0.f};
  #pragma unroll
  for (int ci = 0; ci < 8; ++ci){
    int c = cg*8 + ci;
    float4 d = *(const float4*)(xb + (size_t)c*L_ + lq);
    xr[ci] = d;
    s1[0]+=d.x; s2[0]+=d.x*d.x;  s1[1]+=d.y; s2[1]+=d.y*d.y;
    s1[2]+=d.z; s2[2]+=d.z*d.z;  s1[3]+=d.w; s2[3]+=d.w*d.w;
  }
  #pragma unroll
  for (int off = 16; off < 64; off <<= 1){
    #pragma unroll
    for (int jj = 0; jj < 4; ++jj){
      s1[jj] += __shfl_xor(s1[jj], off);
      s2[jj] += __shfl_xor(s2[jj], off);
    }
  }
  if (l < 16){
    #pragma unroll
    for (int jj = 0; jj < 4; ++jj){
      redF[w*64 + 4*l + jj] = s1[jj];
      redF[512 + w*64 + 4*l + jj] = s2[jj];
    }
  }
  __syncthreads();
  if (tid < 64){
    float a = 0.f, b2 = 0.f;
    #pragma unroll
    for (int ww = 0; ww < 8; ++ww){ a += redF[ww*64 + tid]; b2 += redF[512 + ww*64 + tid]; }
    float mu = a * (1.f/256.f);
    float var = fmaxf(b2 * (1.f/256.f) - mu*mu, 0.f);
    statsF[2*tid] = mu;
    statsF[2*tid+1] = rsqrtf(var + 1e-5f);
  }
  __syncthreads();

  u32 praw[4][4];
  #pragma unroll
  for (int jj = 0; jj < 4; ++jj){
    int t = 4*q4 + jj;
    float mu = statsF[2*t], rs = statsF[2*t+1];
    u32 aw[4];
    #pragma unroll
    for (int cp = 0; cp < 4; ++cp){
      int c0c = cg*8 + 2*cp;
      float v0 = ((const float*)&xr[2*cp])[jj];
      float v1 = ((const float*)&xr[2*cp+1])[jj];
      aw[cp] = pack2((v0-mu)*rs*n1w[c0c] + n1b[c0c], (v1-mu)*rs*n1w[c0c+1] + n1b[c0c+1]);
      praw[jj][cp] = pack2(v0, v1);
    }
    *(uint4*)((char*)Buf1 + t*512 + ((cg*16) ^ ((t&7)<<4))) = make_uint4(aw[0],aw[1],aw[2],aw[3]);
  }
  __syncthreads();

  {
    f32x4 acc[4][2]; ZERO_ACC(acc);
    gemmF(Buf1, pkq + 65536, l, ntb, acc);
    #pragma unroll
    for (int m = 0; m < 4; ++m)
      #pragma unroll
      for (int n2 = 0; n2 < 2; ++n2)
        #pragma unroll
        for (int jj = 0; jj < 4; ++jj){
          int t = m*16 + ((l>>4)<<2) + jj;
          int c = (w<<5) + (n2<<4) + (l&15);
          *(u16*)((char*)Buf2 + t*512 + ((2*c) ^ ((t&7)<<4))) = f2bf(acc[m][n2][jj]);
        }
  }
  __syncthreads();

  const int hh = (tid >> 3) & 7, rr = tid & 7;
  const int tq = w*8 + rr;
  u32 kr[16];
  #pragma unroll
  for (int g = 0; g < 4; ++g){
    uint4 dk = *(const uint4*)((char*)Buf2 + tq*512 + ((hh*64 + 16*g) ^ ((tq&7)<<4)));
    kr[g*4+0] = dk.x; kr[g*4+1] = dk.y; kr[g*4+2] = dk.z; kr[g*4+3] = dk.w;
  }
  __syncthreads();

  {
    f32x4 acc[4][2]; ZERO_ACC(acc);
    gemmF(Buf1, pkq, l, ntb, acc);
    #pragma unroll
    for (int m = 0; m < 4; ++m)
      #pragma unroll
      for (int n2 = 0; n2 < 2; ++n2)
        #pragma unroll
        for (int jj = 0; jj < 4; ++jj){
          int t = m*16 + ((l>>4)<<2) + jj;
          int c = (w<<5) + (n2<<4) + (l&15);
          *(u16*)((char*)Buf2 + t*512 + ((2*c) ^ ((t&7)<<4))) = f2bf(acc[m][n2][jj]);
        }
  }
  __syncthreads();

  float pr[8];
  {
    float qf[32];
    #pragma unroll
    for (int g = 0; g < 4; ++g){
      uint4 dq = *(const uint4*)((char*)Buf2 + tq*512 + ((hh*64 + 16*g) ^ ((tq&7)<<4)));
      qf[g*8+0] = bf2f((u16)dq.x); qf[g*8+1] = bf2f((u16)(dq.x>>16));
      qf[g*8+2] = bf2f((u16)dq.y); qf[g*8+3] = bf2f((u16)(dq.y>>16));
      qf[g*8+4] = bf2f((u16)dq.z); qf[g*8+5] = bf2f((u16)(dq.z>>16));
      qf[g*8+6] = bf2f((u16)dq.w); qf[g*8+7] = bf2f((u16)(dq.w>>16));
    }
    float s[8];
    #pragma unroll
    for (int j = 0; j < 8; ++j){
      float dot = 0.f;
      #pragma unroll
      for (int reg = 0; reg < 16; ++reg){
        u32 kj = (u32)__shfl((int)kr[reg], j, 8);
        dot += qf[2*reg]   * bf2f((u16)kj);
        dot += qf[2*reg+1] * bf2f((u16)(kj>>16));
      }
      s[j] = dot * 0.17677669529663687f;
    }
    float mx = s[0];
    #pragma unroll
    for (int j = 1; j < 8; ++j) mx = fmaxf(mx, s[j]);
    float sum = 0.f;
    #pragma unroll
    for (int j = 0; j < 8; ++j){ pr[j] = __expf(s[j]-mx); sum += pr[j]; }
    float inv = 1.0f / sum;
    #pragma unroll
    for (int j = 0; j < 8; ++j) pr[j] *= inv;
  }
  __syncthreads();

  {
    f32x4 acc[4][2]; ZERO_ACC(acc);
    gemmF(Buf1, pkq + 131072, l, ntb, acc);
    __syncthreads();
    #pragma unroll
    for (int m = 0; m < 4; ++m)
      #pragma unroll
      for (int n2 = 0; n2 < 2; ++n2)
        #pragma unroll
        for (int jj = 0; jj < 4; ++jj){
          int t = m*16 + ((l>>4)<<2) + jj;
          int c = (w<<5) + (n2<<4) + (l&15);
          *(u16*)((char*)Buf2 + t*512 + ((2*c) ^ ((t&7)<<4))) = f2bf(acc[m][n2][jj]);
        }
    #pragma unroll
    for (int jj = 0; jj < 4; ++jj){
      int t = 4*q4 + jj;
      *(uint4*)((char*)Buf1 + t*512 + ((cg*16) ^ ((t&7)<<4))) =
          make_uint4(praw[jj][0], praw[jj][1], praw[jj][2], praw[jj][3]);
    }
  }
  __syncthreads();

  {
    u32 vr[16];
    #pragma unroll
    for (int g = 0; g < 4; ++g){
      uint4 dv = *(const uint4*)((char*)Buf2 + tq*512 + ((hh*64 + 16*g) ^ ((tq&7)<<4)));
      vr[g*4+0] = dv.x; vr[g*4+1] = dv.y; vr[g*4+2] = dv.z; vr[g*4+3] = dv.w;
    }
    float of[32];
    #pragma unroll
    for (int d = 0; d < 32; ++d) of[d] = 0.f;
    #pragma unroll
    for (int j = 0; j < 8; ++j){
      float pj = pr[j];
      #pragma unroll
      for (int reg = 0; reg < 16; ++reg){
        u32 vj = (u32)__shfl((int)vr[reg], j, 8);
        of[2*reg]   += pj*bf2f((u16)vj);
        of[2*reg+1] += pj*bf2f((u16)(vj>>16));
      }
    }
    #pragma unroll
    for (int g = 0; g < 4; ++g){
      uint4 o;
      o.x = pack2(of[g*8+0], of[g*8+1]);
      o.y = pack2(of[g*8+2], of[g*8+3]);
      o.z = pack2(of[g*8+4], of[g*8+5]);
      o.w = pack2(of[g*8+6], of[g*8+7]);
      *(uint4*)((char*)Buf2 + tq*512 + ((hh*64 + 16*g) ^ ((tq&7)<<4))) = o;
    }
  }
  __syncthreads();

  u32 xt1p[4][2][2];
  {
    f32x4 acc[4][2]; ZERO_ACC(acc);
    gemmF(Buf2, pkp, l, ntb, acc);
    __syncthreads();
    #pragma unroll
    for (int m = 0; m < 4; ++m)
      #pragma unroll
      for (int n2 = 0; n2 < 2; ++n2){
        float vv[4];
        #pragma unroll
        for (int jj = 0; jj < 4; ++jj){
          int t = m*16 + ((l>>4)<<2) + jj;
          int c = (w<<5) + (n2<<4) + (l&15);
          float rv = bf2f(*(const u16*)((char*)Buf1 + t*512 + ((2*c) ^ ((t&7)<<4))));
          float v = acc[m][n2][jj] + projb[c] + rv;
          vv[jj] = v;
          *(u16*)((char*)Buf2 + t*512 + 2*c) = f2bf(v);
        }
        xt1p[m][n2][0] = pack2(vv[0], vv[1]);
        xt1p[m][n2][1] = pack2(vv[2], vv[3]);
      }
  }
  __syncthreads();

  {
    float4 wv = *(const float4*)(n2w + 4*l);
    float4 bv = *(const float4*)(n2b + 4*l);
    #pragma unroll 1
    for (int r = 0; r < 8; ++r){
      int t = w*8 + r;
      uint2 d = *(const uint2*)((char*)Buf2 + t*512 + 8*l);
      float f0 = bf2f((u16)d.x), f1 = bf2f((u16)(d.x>>16));
      float f2 = bf2f((u16)d.y), f3 = bf2f((u16)(d.y>>16));
      float ls1 = f0+f1+f2+f3;
      float ls2 = f0*f0+f1*f1+f2*f2+f3*f3;
      #pragma unroll
      for (int off = 1; off < 64; off <<= 1){
        ls1 += __shfl_xor(ls1, off);
        ls2 += __shfl_xor(ls2, off);
      }
      float mu = ls1 * (1.f/256.f);
      float var = fmaxf(ls2 * (1.f/256.f) - mu*mu, 0.f);
      float rs = rsqrtf(var + 1e-5f);
      uint2 pp;
      pp.x = pack2((f0-mu)*rs*wv.x+bv.x, (f1-mu)*rs*wv.y+bv.y);
      pp.y = pack2((f2-mu)*rs*wv.z+bv.z, (f3-mu)*rs*wv.w+bv.w);
      *(uint2*)((char*)Buf1 + t*512 + ((8*l) ^ ((t&7)<<4))) = pp;
    }
  }
  __syncthreads();

  f32x4 acc2[4][2]; ZERO_ACC(acc2);
  #pragma unroll 1
  for (int c2 = 0; c2 < 4; ++c2){
    f32x4 acc1[4][2]; ZERO_ACC(acc1);
    gemmF(Buf1, pk1 + (size_t)c2*65536, l, ntb, acc1);
    __syncthreads();
    #pragma unroll
    for (int m = 0; m < 4; ++m)
      #pragma unroll
      for (int n2 = 0; n2 < 2; ++n2)
        #pragma unroll
        for (int jj = 0; jj < 4; ++jj){
          int t = m*16 + ((l>>4)<<2) + jj;
          int c = (w<<5) + (n2<<4) + (l&15);
          float xv = acc1[m][n2][jj] + f1b[c2*256 + c];
          float u = xv*(0.79788456f + 0.035677408f*xv*xv);
          float g = xv / (1.f + __expf(-2.f*u));
          *(u16*)((char*)Buf2 + t*512 + ((2*c) ^ ((t&7)<<4))) = f2bf(g);
        }
    __syncthreads();
    gemmF(Buf2, pk2 + (size_t)c2*65536, l, ntb, acc2);
    __syncthreads();
  }

  float* OutF = (float*)smem;
  #pragma unroll
  for (int m = 0; m < 4; ++m)
    #pragma unroll
    for (int n2 = 0; n2 < 2; ++n2)
      #pragma unroll
      for (int jj = 0; jj < 4; ++jj){
        int t = m*16 + ((l>>4)<<2) + jj;
        int c = (w<<5) + (n2<<4) + (l&15);
        u32 p = xt1p[m][n2][jj>>1];
        float rv = bf2f((u16)((jj&1) ? (p>>16) : (p&0xFFFF)));
        float v = acc2[m][n2][jj] + f2b[c] + rv;
        *(float*)((char*)OutF + c*256 + ((4*t) ^ ((c&15)<<4))) = v;
      }
  __syncthreads();

  float* ob = out + (size_t)bb*CL_;
  #pragma unroll
  for (int ii = 0; ii < 8; ++ii){
    int id = tid + ii*512;
    int c = id >> 4, qd = id & 15;
    int lw = l0 + 4*qd; if (lw >= L_) lw -= L_;
    float4 vv = *(const float4*)((char*)OutF + c*256 + ((16*qd) ^ ((c&15)<<4)));
    *(float4*)(ob + (size_t)c*L_ + lw) = vv;
  }
}

// ---------------- launch ----------------
extern "C" void kernel_launch(void* const* d_in, const int* in_sizes, int n_in,
                              void* d_out, int out_size, void* d_ws, size_t ws_size,
                              hipStream_t stream)
{
  const float* x     = (const float*)d_in[0];
  const float* n1w   = (const float*)d_in[1];
  const float* n1b   = (const float*)d_in[2];
  const float* n2w   = (const float*)d_in[3];
  const float* n2b   = (const float*)d_in[4];
  const float* qkvw  = (const float*)d_in[5];
  const float* projw = (const float*)d_in[6];
  const float* projb = (const float*)d_in[7];
  const float* f1w   = (const float*)d_in[8];
  const float* f1b   = (const float*)d_in[9];
  const float* f2w   = (const float*)d_in[10];
  const float* f2b   = (const float*)d_in[11];
  float* out = (float*)d_out;

  u16* ws  = (u16*)d_ws;
  u16* pkq = ws;                        // 3*65536 u16
  u16* pkp = pkq + 196608;              // 65536
  u16* pk1 = pkp + 65536;               // 4*65536
  u16* pk2 = pk1 + 262144;              // 262144  -> weights total 786432 u16 (1.57 MB)
  u16* xt1g = pk2 + 262144;             // 8*256*16384 u16 = 67.1 MB
  float* statsg = (float*)(xt1g + (size_t)8*CL_);   // 1.05 MB

  size_t need = (size_t)786432*2 + (size_t)8*CL_*2 + (size_t)8*16384*2*4;

  hipLaunchKernelGGL(wpack_kernel, dim3(384), dim3(256), 0, stream,
                     qkvw, projw, f1w, f2w, pkq, pkp, pk1, pk2);
  if (ws_size >= need){
    hipLaunchKernelGGL(swin_attn_kernel, dim3(2048), dim3(512), 0, stream,
                       x, n1w, n1b, pkq, pkp, projb, xt1g, statsg);
    hipLaunchKernelGGL(swin_ff_kernel, dim3(2048), dim3(512), 0, stream,
                       xt1g, statsg, n2w, n2b, pk1, f1b, pk2, f2b, out);
  } else {
    hipLaunchKernelGGL(swin_fused_kernel, dim3(2048), dim3(512), 0, stream,
                       x, n1w, n1b, n2w, n2b, pkq, pkp, projb, pk1, f1b, pk2, f2b, out);
  }
}

// Round 20
// 411.097 us; speedup vs baseline: 1.0231x; 1.0231x over previous
//
#include <hip/hip_runtime.h>
#include <hip/hip_bf16.h>

#define C_ 256
#define L_ 16384
#define CL_ (C_*L_)

typedef unsigned int u32;
typedef unsigned short u16;
typedef __bf16 bf16_t;
typedef bf16_t bf16x8 __attribute__((ext_vector_type(8)));
typedef float f32x4 __attribute__((ext_vector_type(4)));

__device__ __forceinline__ float bf2f(u16 v){ return __builtin_bit_cast(float, ((u32)v)<<16); }
__device__ __forceinline__ u16 f2bf(float f){
  bf16_t h = (bf16_t)f;
  return __builtin_bit_cast(u16, h);
}
__device__ __forceinline__ u32 pack2(float a, float b){
  return (u32)f2bf(a) | ((u32)f2bf(b)<<16);
}

#define AST 528    // A-tile stride (64 x 264 u16), affine + conflict-free
#define HST 272    // BufH stride (64 x 136 u16)
#define CST 136    // c-major stride (256 x 68 u16)
#define OST 68     // OutF stride (floats)

// ---------------- weight PACK kernel ----------------
__global__ void wpack_kernel(const float* __restrict__ qkvw, const float* __restrict__ projw,
                             const float* __restrict__ f1w, const float* __restrict__ f2w,
                             u16* __restrict__ pq, u16* __restrict__ pp,
                             u16* __restrict__ p1, u16* __restrict__ p2)
{
  int bid = blockIdx.x, tid = threadIdx.x;
  const float* src; u16* dst; int stride, n, k;
  if (bid < 96){
    int f = bid*256 + tid;
    int l = f & 63, nt = (f>>6) & 15, kk = f>>10;
    int s = kk>>3, ks = kk&7;
    stride = 768; src = qkvw;
    n = s*256 + nt*16 + (l&15);
    k = ks*32 + ((l>>4)<<3);
    dst = pq + (size_t)s*65536 + ((size_t)(ks*16 + nt)*64 + l)*8;
  } else if (bid < 128){
    int f = (bid-96)*256 + tid;
    int l = f & 63, nt = (f>>6) & 15, ks = f>>10;
    stride = 256; src = projw;
    n = nt*16 + (l&15);
    k = ks*32 + ((l>>4)<<3);
    dst = pp + ((size_t)(ks*16 + nt)*64 + l)*8;
  } else if (bid < 256){
    int f = (bid-128)*256 + tid;
    int l = f & 63, nt = (f>>6) & 15, kk = f>>10;
    int c2 = kk>>3, ks = kk&7;
    stride = 1024; src = f1w;
    n = c2*256 + nt*16 + (l&15);
    k = ks*32 + ((l>>4)<<3);
    dst = p1 + (size_t)c2*65536 + ((size_t)(ks*16 + nt)*64 + l)*8;
  } else {
    int f = (bid-256)*256 + tid;
    int l = f & 63, nt = (f>>6) & 15, ks = f>>10;
    stride = 256; src = f2w;
    n = nt*16 + (l&15);
    k = ks*32 + ((l>>4)<<3);
    dst = p2 + ((size_t)(ks*16 + nt)*64 + l)*8;
  }
  u16 v[8];
  #pragma unroll
  for (int j = 0; j < 8; ++j) v[j] = f2bf(src[(size_t)(k+j)*stride + n]);
  uint4 o;
  o.x = (u32)v[0] | ((u32)v[1]<<16);
  o.y = (u32)v[2] | ((u32)v[3]<<16);
  o.z = (u32)v[4] | ((u32)v[5]<<16);
  o.w = (u32)v[6] | ((u32)v[7]<<16);
  *(uint4*)dst = o;
}

// ---------------- padded-layout GEMM helpers ----------------
__device__ __forceinline__ void gemmP(const u16* Abase, const u16* __restrict__ pk,
                                      int l, int ntb, f32x4 acc[4][2])
{
  const char* ab = (const char*)Abase + (l&15)*AST + ((l>>4)<<4);
  const u16* bp = pk + ((size_t)ntb*64 + l)*8;
  #pragma unroll
  for (int ks = 0; ks < 8; ++ks){
    const u16* bk = bp + (size_t)ks*8192;
    bf16x8 b0 = *(const bf16x8*)(bk);
    bf16x8 b1 = *(const bf16x8*)(bk + 512);
    bf16x8 a[4];
    #pragma unroll
    for (int m = 0; m < 4; ++m)
      a[m] = *(const bf16x8*)(ab + m*(16*AST) + ks*64);
    #pragma unroll
    for (int m = 0; m < 4; ++m){
      acc[m][0] = __builtin_amdgcn_mfma_f32_16x16x32_bf16(a[m], b0, acc[m][0], 0, 0, 0);
      acc[m][1] = __builtin_amdgcn_mfma_f32_16x16x32_bf16(a[m], b1, acc[m][1], 0, 0, 0);
    }
  }
}
#define ZERO_ACC(A) { _Pragma("unroll") for (int m_ = 0; m_ < 4; ++m_){ A[m_][0] = (f32x4){0,0,0,0}; A[m_][1] = (f32x4){0,0,0,0}; } }

// merged Q/K/V GEMM: A loaded once, 24 MFMAs per K-step
__device__ __forceinline__ void gemmP3(const u16* Abase, const u16* __restrict__ pkq,
                                       int l, int ntb,
                                       f32x4 aq[4][2], f32x4 ak[4][2], f32x4 av[4][2])
{
  const char* ab = (const char*)Abase + (l&15)*AST + ((l>>4)<<4);
  const u16* bq = pkq + ((size_t)ntb*64 + l)*8;
  #pragma unroll
  for (int ks = 0; ks < 8; ++ks){
    const u16* bkq = bq + (size_t)ks*8192;
    bf16x8 q0 = *(const bf16x8*)(bkq);
    bf16x8 q1 = *(const bf16x8*)(bkq + 512);
    bf16x8 k0 = *(const bf16x8*)(bkq + 65536);
    bf16x8 k1 = *(const bf16x8*)(bkq + 65536 + 512);
    bf16x8 v0 = *(const bf16x8*)(bkq + 131072);
    bf16x8 v1 = *(const bf16x8*)(bkq + 131072 + 512);
    bf16x8 a[4];
    #pragma unroll
    for (int m = 0; m < 4; ++m)
      a[m] = *(const bf16x8*)(ab + m*(16*AST) + ks*64);
    #pragma unroll
    for (int m = 0; m < 4; ++m){
      aq[m][0] = __builtin_amdgcn_mfma_f32_16x16x32_bf16(a[m], q0, aq[m][0], 0, 0, 0);
      aq[m][1] = __builtin_amdgcn_mfma_f32_16x16x32_bf16(a[m], q1, aq[m][1], 0, 0, 0);
      ak[m][0] = __builtin_amdgcn_mfma_f32_16x16x32_bf16(a[m], k0, ak[m][0], 0, 0, 0);
      ak[m][1] = __builtin_amdgcn_mfma_f32_16x16x32_bf16(a[m], k1, ak[m][1], 0, 0, 0);
      av[m][0] = __builtin_amdgcn_mfma_f32_16x16x32_bf16(a[m], v0, av[m][0], 0, 0, 0);
      av[m][1] = __builtin_amdgcn_mfma_f32_16x16x32_bf16(a[m], v1, av[m][1], 0, 0, 0);
    }
  }
}

// old-layout GEMM for fallback kernel
__device__ __forceinline__ void gemmF(const u16* Abase, const u16* __restrict__ pk,
                                      int l, int ntb, f32x4 acc[4][2])
{
  #pragma unroll
  for (int ks = 0; ks < 8; ++ks){
    bf16x8 b0 = *(const bf16x8*)(pk + ((size_t)(ks*16 + ntb    )*64 + l)*8);
    bf16x8 b1 = *(const bf16x8*)(pk + ((size_t)(ks*16 + ntb + 1)*64 + l)*8);
    int k0 = ks*32;
    bf16x8 a[4];
    #pragma unroll
    for (int m = 0; m < 4; ++m){
      int t = m*16 + (l & 15);
      int off = t*512 + ((2*(k0 + ((l>>4)<<3))) ^ ((t&7)<<4));
      a[m] = *(const bf16x8*)((const char*)Abase + off);
    }
    #pragma unroll
    for (int m = 0; m < 4; ++m){
      acc[m][0] = __builtin_amdgcn_mfma_f32_16x16x32_bf16(a[m], b0, acc[m][0], 0, 0, 0);
      acc[m][1] = __builtin_amdgcn_mfma_f32_16x16x32_bf16(a[m], b1, acc[m][1], 0, 0, 0);
    }
  }
}

// ================= kernel 1: LN1 + attention (merged QKV, 3-buffer phase-compressed) =================
// LDS: Buf1 [0,33792) | BufK [33792,67584) | BufQ [67584,102400) (34816 B for c-major xt1) |
// redF/statsF at 102400 (4608 B). Total 107008 B, 1 block/CU.
__launch_bounds__(512, 2)
__global__ void swin_attn_kernel(const float* __restrict__ x,
                                 const float* __restrict__ n1w, const float* __restrict__ n1b,
                                 const u16* __restrict__ pkq, const u16* __restrict__ pkp,
                                 const float* __restrict__ projb,
                                 u16* __restrict__ xt1g, float* __restrict__ statsg)
{
  __shared__ char smem[107008];
  u16* Buf1 = (u16*)smem;                  // [64][264] A-ln1 -> raw x
  char* BufK = smem + 33792;               // [64][264] K -> O
  char* BufQ = smem + 67584;               // [64][264] Q -> V -> [256][68] c-major xt1
  float* redF = (float*)(smem + 102400);   // [2][8][64] partials
  float* statsF = redF + 1024;             // [64][2]

  const int tid = threadIdx.x;
  const int w = tid >> 6;
  const int l = tid & 63;
  const int bb = blockIdx.x >> 8;
  const int blkl = blockIdx.x & 255;
  const int l0 = blkl*64 + 4;
  const float* xb = x + (size_t)bb*CL_;
  const int ntb = w*2;

  // ---- LN1 ----
  const int q4 = tid & 15, cg = tid >> 4;
  int lq = l0 + 4*q4; if (lq >= L_) lq -= L_;
  u32 praw[4][4];
  {
    float4 xr[8];
    float s1[4] = {0.f,0.f,0.f,0.f};
    float s2[4] = {0.f,0.f,0.f,0.f};
    #pragma unroll
    for (int ci = 0; ci < 8; ++ci){
      int c = cg*8 + ci;
      float4 d = *(const float4*)(xb + (size_t)c*L_ + lq);
      xr[ci] = d;
      s1[0]+=d.x; s2[0]+=d.x*d.x;  s1[1]+=d.y; s2[1]+=d.y*d.y;
      s1[2]+=d.z; s2[2]+=d.z*d.z;  s1[3]+=d.w; s2[3]+=d.w*d.w;
    }
    #pragma unroll
    for (int off = 16; off < 64; off <<= 1){
      #pragma unroll
      for (int jj = 0; jj < 4; ++jj){
        s1[jj] += __shfl_xor(s1[jj], off);
        s2[jj] += __shfl_xor(s2[jj], off);
      }
    }
    if (l < 16){
      #pragma unroll
      for (int jj = 0; jj < 4; ++jj){
        redF[w*64 + 4*l + jj] = s1[jj];
        redF[512 + w*64 + 4*l + jj] = s2[jj];
      }
    }
    __syncthreads();
    if (tid < 64){
      float a = 0.f, b2 = 0.f;
      #pragma unroll
      for (int ww = 0; ww < 8; ++ww){ a += redF[ww*64 + tid]; b2 += redF[512 + ww*64 + tid]; }
      float mu = a * (1.f/256.f);
      float var = fmaxf(b2 * (1.f/256.f) - mu*mu, 0.f);
      statsF[2*tid] = mu;
      statsF[2*tid+1] = rsqrtf(var + 1e-5f);
    }
    __syncthreads();
    #pragma unroll
    for (int jj = 0; jj < 4; ++jj){
      int t = 4*q4 + jj;
      float mu = statsF[2*t], rs = statsF[2*t+1];
      u32 aw[4];
      #pragma unroll
      for (int cp = 0; cp < 4; ++cp){
        int c0c = cg*8 + 2*cp;
        float v0 = ((const float*)&xr[2*cp])[jj];
        float v1 = ((const float*)&xr[2*cp+1])[jj];
        aw[cp] = pack2((v0-mu)*rs*n1w[c0c] + n1b[c0c], (v1-mu)*rs*n1w[c0c+1] + n1b[c0c+1]);
        praw[jj][cp] = pack2(v0, v1);
      }
      *(uint4*)((char*)Buf1 + t*AST + cg*16) = make_uint4(aw[0],aw[1],aw[2],aw[3]);
    }
  }
  __syncthreads();                          // A: A-ln1 ready

  // ---- merged Q/K/V GEMM ----
  f32x4 aq[4][2], ak[4][2], av[4][2];
  ZERO_ACC(aq); ZERO_ACC(ak); ZERO_ACC(av);
  gemmP3(Buf1, pkq, l, ntb, aq, ak, av);

  // ---- retire K -> BufK and Q -> BufQ (no intervening barrier) ----
  #pragma unroll
  for (int m = 0; m < 4; ++m)
    #pragma unroll
    for (int n2 = 0; n2 < 2; ++n2)
      #pragma unroll
      for (int jj = 0; jj < 4; ++jj){
        int t = m*16 + ((l>>4)<<2) + jj;
        int c = (w<<5) + (n2<<4) + (l&15);
        *(u16*)(BufK + t*AST + 2*c) = f2bf(ak[m][n2][jj]);
        *(u16*)(BufQ + t*AST + 2*c) = f2bf(aq[m][n2][jj]);
      }
  __syncthreads();                          // B: K,Q ready

  // ---- read kr + qf in ONE phase ----
  const int hh = (tid >> 3) & 7, rr = tid & 7;
  const int tq = w*8 + rr;
  u32 kr[16];
  float qf[32];
  #pragma unroll
  for (int g = 0; g < 4; ++g){
    uint4 dk = *(const uint4*)(BufK + tq*AST + hh*64 + 16*g);
    kr[g*4+0] = dk.x; kr[g*4+1] = dk.y; kr[g*4+2] = dk.z; kr[g*4+3] = dk.w;
    uint4 dq = *(const uint4*)(BufQ + tq*AST + hh*64 + 16*g);
    qf[g*8+0] = bf2f((u16)dq.x); qf[g*8+1] = bf2f((u16)(dq.x>>16));
    qf[g*8+2] = bf2f((u16)dq.y); qf[g*8+3] = bf2f((u16)(dq.y>>16));
    qf[g*8+4] = bf2f((u16)dq.z); qf[g*8+5] = bf2f((u16)(dq.z>>16));
    qf[g*8+6] = bf2f((u16)dq.w); qf[g*8+7] = bf2f((u16)(dq.w>>16));
  }
  __syncthreads();                          // C: all Q reads done

  // ---- retire V -> BufQ; dump praw -> Buf1; softmax ----
  #pragma unroll
  for (int m = 0; m < 4; ++m)
    #pragma unroll
    for (int n2 = 0; n2 < 2; ++n2)
      #pragma unroll
      for (int jj = 0; jj < 4; ++jj){
        int t = m*16 + ((l>>4)<<2) + jj;
        int c = (w<<5) + (n2<<4) + (l&15);
        *(u16*)(BufQ + t*AST + 2*c) = f2bf(av[m][n2][jj]);
      }
  #pragma unroll
  for (int jj = 0; jj < 4; ++jj){
    int t = 4*q4 + jj;
    *(uint4*)((char*)Buf1 + t*AST + cg*16) =
        make_uint4(praw[jj][0], praw[jj][1], praw[jj][2], praw[jj][3]);
  }
  float pr[8];
  {
    float s[8];
    #pragma unroll
    for (int j = 0; j < 8; ++j){
      float dot = 0.f;
      #pragma unroll
      for (int reg = 0; reg < 16; ++reg){
        u32 kj = (u32)__shfl((int)kr[reg], j, 8);
        dot += qf[2*reg]   * bf2f((u16)kj);
        dot += qf[2*reg+1] * bf2f((u16)(kj>>16));
      }
      s[j] = dot * 0.17677669529663687f;
    }
    float mx = s[0];
    #pragma unroll
    for (int j = 1; j < 8; ++j) mx = fmaxf(mx, s[j]);
    float sum = 0.f;
    #pragma unroll
    for (int j = 0; j < 8; ++j){ pr[j] = __expf(s[j]-mx); sum += pr[j]; }
    float inv = 1.0f / sum;
    #pragma unroll
    for (int j = 0; j < 8; ++j) pr[j] *= inv;
  }
  __syncthreads();                          // D: V ready

  // ---- PV: read V rows, write O -> BufK ----
  {
    u32 vr[16];
    #pragma unroll
    for (int g = 0; g < 4; ++g){
      uint4 dv = *(const uint4*)(BufQ + tq*AST + hh*64 + 16*g);
      vr[g*4+0] = dv.x; vr[g*4+1] = dv.y; vr[g*4+2] = dv.z; vr[g*4+3] = dv.w;
    }
    float of[32];
    #pragma unroll
    for (int d = 0; d < 32; ++d) of[d] = 0.f;
    #pragma unroll
    for (int j = 0; j < 8; ++j){
      float pj = pr[j];
      #pragma unroll
      for (int reg = 0; reg < 16; ++reg){
        u32 vj = (u32)__shfl((int)vr[reg], j, 8);
        of[2*reg]   += pj*bf2f((u16)vj);
        of[2*reg+1] += pj*bf2f((u16)(vj>>16));
      }
    }
    #pragma unroll
    for (int g = 0; g < 4; ++g){
      uint4 o;
      o.x = pack2(of[g*8+0], of[g*8+1]);
      o.y = pack2(of[g*8+2], of[g*8+3]);
      o.z = pack2(of[g*8+4], of[g*8+5]);
      o.w = pack2(of[g*8+6], of[g*8+7]);
      *(uint4*)(BufK + tq*AST + hh*64 + 16*g) = o;
    }
  }
  __syncthreads();                          // E: O ready

  // ---- proj GEMM (A=BufK) + epi -> BufQ c-major xt1 ----
  {
    f32x4 acc[4][2]; ZERO_ACC(acc);
    gemmP((const u16*)BufK, pkp, l, ntb, acc);
    #pragma unroll
    for (int m = 0; m < 4; ++m)
      #pragma unroll
      for (int n2 = 0; n2 < 2; ++n2)
        #pragma unroll
        for (int jj = 0; jj < 4; ++jj){
          int t = m*16 + ((l>>4)<<2) + jj;
          int c = (w<<5) + (n2<<4) + (l&15);
          float rv = bf2f(*(const u16*)((char*)Buf1 + t*AST + 2*c));
          float v = acc[m][n2][jj] + projb[c] + rv;
          *(u16*)(BufQ + c*CST + 2*t) = f2bf(v);
        }
  }
  __syncthreads();                          // G: xt1 tile ready

  // ---- LN2 stats partials + xt1 global write ----
  {
    float a = 0.f, b2 = 0.f;
    #pragma unroll
    for (int ci = 0; ci < 32; ++ci){
      int c = (w<<5) + ci;
      float v = bf2f(*(const u16*)(BufQ + c*CST + 2*l));
      a += v; b2 += v*v;
    }
    redF[w*64 + l] = a;
    redF[512 + w*64 + l] = b2;
  }
  u16* xo = xt1g + (size_t)bb*CL_;
  #pragma unroll
  for (int ii = 0; ii < 8; ++ii){
    int id = tid + ii*512;
    int c = id >> 4, qd = id & 15;
    int lw = l0 + 4*qd; if (lw >= L_) lw -= L_;
    uint2 dd = *(const uint2*)(BufQ + c*CST + 8*qd);
    *(uint2*)(xo + (size_t)c*L_ + lw) = dd;
  }
  __syncthreads();                          // H
  if (tid < 64){
    float a = 0.f, b2 = 0.f;
    #pragma unroll
    for (int ww = 0; ww < 8; ++ww){ a += redF[ww*64 + tid]; b2 += redF[512 + ww*64 + tid]; }
    float mu = a * (1.f/256.f);
    float var = fmaxf(b2 * (1.f/256.f) - mu*mu, 0.f);
    float2 st; st.x = mu; st.y = rsqrtf(var + 1e-5f);
    *(float2*)(statsg + (size_t)(bb*16384 + blkl*64 + tid)*2) = st;
  }
}

// ================= kernel 2: LN2 + FF (pair-merged ff1, __expf GELU) =================
__launch_bounds__(512, 4)
__global__ void swin_ff_kernel(const u16* __restrict__ xt1g, const float* __restrict__ statsg,
                               const float* __restrict__ n2w, const float* __restrict__ n2b,
                               const u16* __restrict__ pk1, const float* __restrict__ f1b,
                               const u16* __restrict__ pk2, const float* __restrict__ f2b,
                               float* __restrict__ out)
{
  __shared__ char smem[68608];
  u16* Buf1  = (u16*)smem;               // [64][264] A-ln2 (33792 B)
  char* BufH0 = smem + 33792;            // [64][136] H chunk j0 (17408 B)
  char* BufH1 = smem + 51200;            // [64][136] H chunk j1

  const int tid = threadIdx.x;
  const int w = tid >> 6;
  const int l = tid & 63;
  const int bb = blockIdx.x >> 8;
  const int blkl = blockIdx.x & 255;
  const int l0 = blkl*64 + 4;
  const u16* xi = xt1g + (size_t)bb*CL_;

  // ---- load xt1 (c-major) + LN2-normalize -> Buf1 ----
  const int q4 = tid & 15, cg = tid >> 4;
  int lq = l0 + 4*q4; if (lq >= L_) lq -= L_;
  {
    u32 xl[8][2];
    #pragma unroll
    for (int ci = 0; ci < 8; ++ci){
      int c = cg*8 + ci;
      uint2 dd = *(const uint2*)(xi + (size_t)c*L_ + lq);
      xl[ci][0] = dd.x; xl[ci][1] = dd.y;
    }
    #pragma unroll
    for (int jj = 0; jj < 4; ++jj){
      int t = 4*q4 + jj;
      float2 st = *(const float2*)(statsg + (size_t)(bb*16384 + blkl*64 + t)*2);
      float mu = st.x, rs = st.y;
      u32 aw[4];
      #pragma unroll
      for (int cp = 0; cp < 4; ++cp){
        int c0c = cg*8 + 2*cp;
        float v0 = bf2f((u16)(xl[2*cp  ][jj>>1] >> (16*(jj&1))));
        float v1 = bf2f((u16)(xl[2*cp+1][jj>>1] >> (16*(jj&1))));
        aw[cp] = pack2((v0-mu)*rs*n2w[c0c] + n2b[c0c], (v1-mu)*rs*n2w[c0c+1] + n2b[c0c+1]);
      }
      *(uint4*)((char*)Buf1 + t*AST + cg*16) = make_uint4(aw[0],aw[1],aw[2],aw[3]);
    }
  }
  __syncthreads();

  // ---- FF: 4 pair-steps; ff1 merged over chunk pair ----
  f32x4 acc2[4][2]; ZERO_ACC(acc2);
  const char* ab1 = (const char*)Buf1 + (l&15)*AST + ((l>>4)<<4);
  #pragma unroll 1
  for (int jp = 0; jp < 4; ++jp){
    f32x4 a1a[4], a1b[4];
    #pragma unroll
    for (int m = 0; m < 4; ++m){ a1a[m] = (f32x4){0,0,0,0}; a1b[m] = (f32x4){0,0,0,0}; }
    const u16* p1 = pk1 + (size_t)jp*65536;
    const u16* bpA = p1 + ((size_t)(w    )*64 + l)*8;
    const u16* bpB = p1 + ((size_t)(8 + w)*64 + l)*8;
    #pragma unroll
    for (int ks = 0; ks < 8; ++ks){
      bf16x8 bA = *(const bf16x8*)(bpA + (size_t)ks*8192);
      bf16x8 bB = *(const bf16x8*)(bpB + (size_t)ks*8192);
      #pragma unroll
      for (int m = 0; m < 4; ++m){
        bf16x8 a = *(const bf16x8*)(ab1 + m*(16*AST) + ks*64);
        a1a[m] = __builtin_amdgcn_mfma_f32_16x16x32_bf16(a, bA, a1a[m], 0, 0, 0);
        a1b[m] = __builtin_amdgcn_mfma_f32_16x16x32_bf16(a, bB, a1b[m], 0, 0, 0);
      }
    }
    // GELU both chunks -> BufH0 / BufH1 (sigmoid form, native v_exp via __expf)
    #pragma unroll
    for (int m = 0; m < 4; ++m)
      #pragma unroll
      for (int jj = 0; jj < 4; ++jj){
        int t = m*16 + ((l>>4)<<2) + jj;
        int cp_ = (w<<4) + (l&15);
        float xa = a1a[m][jj] + f1b[(2*jp)*128 + cp_];
        float ua = xa*(0.79788456f + 0.035677408f*xa*xa);
        *(u16*)(BufH0 + t*HST + 2*cp_) = f2bf(xa / (1.f + __expf(-2.f*ua)));
        float xb = a1b[m][jj] + f1b[(2*jp+1)*128 + cp_];
        float ub = xb*(0.79788456f + 0.035677408f*xb*xb);
        *(u16*)(BufH1 + t*HST + 2*cp_) = f2bf(xb / (1.f + __expf(-2.f*ub)));
      }
    __syncthreads();                 // H pair ready
    const u16* bp2 = pk2 + ((size_t)((8*jp)*16 + 2*w)*64 + l)*8;
    #pragma unroll
    for (int kk = 0; kk < 8; ++kk){
      const char* hb = (kk < 4) ? BufH0 : BufH1;
      const char* abh = hb + (l&15)*HST + ((l>>4)<<4);
      int ksl = kk & 3;
      const u16* bk = bp2 + (size_t)kk*8192;
      bf16x8 b0 = *(const bf16x8*)(bk);
      bf16x8 b1 = *(const bf16x8*)(bk + 512);
      bf16x8 a[4];
      #pragma unroll
      for (int m = 0; m < 4; ++m)
        a[m] = *(const bf16x8*)(abh + m*(16*HST) + ksl*64);
      #pragma unroll
      for (int m = 0; m < 4; ++m){
        acc2[m][0] = __builtin_amdgcn_mfma_f32_16x16x32_bf16(a[m], b0, acc2[m][0], 0, 0, 0);
        acc2[m][1] = __builtin_amdgcn_mfma_f32_16x16x32_bf16(a[m], b1, acc2[m][1], 0, 0, 0);
      }
    }
    __syncthreads();                 // ff2 reads done before next pair's GELU writes
  }

  // ---- epilogue: +f2b, fp32 stage (padded), +residual on store ----
  float* OutF = (float*)smem;            // [128 rows][68] fp32 padded
  float* ob = out + (size_t)bb*CL_;
  #pragma unroll
  for (int n2p = 0; n2p < 2; ++n2p){
    __syncthreads();
    #pragma unroll
    for (int m = 0; m < 4; ++m)
      #pragma unroll
      for (int jj = 0; jj < 4; ++jj){
        int t = m*16 + ((l>>4)<<2) + jj;
        int c = (w<<5) + (n2p<<4) + (l&15);
        int row = (w<<4) + (l&15);
        float v = acc2[m][n2p][jj] + f2b[c];
        OutF[row*OST + t] = v;
      }
    __syncthreads();
    #pragma unroll
    for (int ii = 0; ii < 4; ++ii){
      int id = tid + ii*512;
      int row = id >> 4, qd = id & 15;
      int cg_ = ((row>>4)<<5) + (n2p<<4) + (row&15);
      int lw = l0 + 4*qd; if (lw >= L_) lw -= L_;
      float4 vv = *(const float4*)(OutF + row*OST + 4*qd);
      uint2 rr2 = *(const uint2*)(xi + (size_t)cg_*L_ + lw);
      vv.x += bf2f((u16)rr2.x);  vv.y += bf2f((u16)(rr2.x>>16));
      vv.z += bf2f((u16)rr2.y);  vv.w += bf2f((u16)(rr2.y>>16));
      *(float4*)(ob + (size_t)cg_*L_ + lw) = vv;
    }
  }
}

// ================= fallback: fused kernel (old layout; used if ws too small) =================
__launch_bounds__(512, 2)
__global__ void swin_fused_kernel(const float* __restrict__ x,
                                  const float* __restrict__ n1w, const float* __restrict__ n1b,
                                  const float* __restrict__ n2w, const float* __restrict__ n2b,
                                  const u16* __restrict__ pkq, const u16* __restrict__ pkp,
                                  const float* __restrict__ projb,
                                  const u16* __restrict__ pk1, const float* __restrict__ f1b,
                                  const u16* __restrict__ pk2, const float* __restrict__ f2b,
                                  float* __restrict__ out)
{
  __shared__ u16 smem[35072];
  u16* Buf1 = smem;
  u16* Buf2 = smem + 16384;
  float* redF   = (float*)(smem + 32768);
  float* statsF = redF + 1024;

  const int tid = threadIdx.x;
  const int w = tid >> 6;
  const int l = tid & 63;
  const int bb = blockIdx.x >> 8;
  const int blkl = blockIdx.x & 255;
  const int l0 = blkl*64 + 4;
  const float* xb = x + (size_t)bb*CL_;
  const int ntb = w*2;

  const int q4 = tid & 15, cg = tid >> 4;
  int lq = l0 + 4*q4; if (lq >= L_) lq -= L_;
  float4 xr[8];
  float s1[4] = {0.f,0.f,0.f,0.f};
  float s2[4] = {0.f,0.f,0.f,0.f};
  #pragma unroll
  for (int ci = 0; ci < 8; ++ci){
    int c = cg*8 + ci;
    float4 d = *(const float4*)(xb + (size_t)c*L_ + lq);
    xr[ci] = d;
    s1[0]+=d.x; s2[0]+=d.x*d.x;  s1[1]+=d.y; s2[1]+=d.y*d.y;
    s1[2]+=d.z; s2[2]+=d.z*d.z;  s1[3]+=d.w; s2[3]+=d.w*d.w;
  }
  #pragma unroll
  for (int off = 16; off < 64; off <<= 1){
    #pragma unroll
    for (int jj = 0; jj < 4; ++jj){
      s1[jj] += __shfl_xor(s1[jj], off);
      s2[jj] += __shfl_xor(s2[jj], off);
    }
  }
  if (l < 16){
    #pragma unroll
    for (int jj = 0; jj < 4; ++jj){
      redF[w*64 + 4*l + jj] = s1[jj];
      redF[512 + w*64 + 4*l + jj] = s2[jj];
    }
  }
  __syncthreads();
  if (tid < 64){
    float a = 0.f, b2 = 0.f;
    #pragma unroll
    for (int ww = 0; ww < 8; ++ww){ a += redF[ww*64 + tid]; b2 += redF[512 + ww*64 + tid]; }
    float mu = a * (1.f/256.f);
    float var = fmaxf(b2 * (1.f/256.f) - mu*mu, 0.f);
    statsF[2*tid] = mu;
    statsF[2*tid+1] = rsqrtf(var + 1e-5f);
  }
  __syncthreads();

  u32 praw[4][4];
  #pragma unroll
  for (int jj = 0; jj < 4; ++jj){
    int t = 4*q4 + jj;
    float mu = statsF[2*t], rs = statsF[2*t+1];
    u32 aw[4];
    #pragma unroll
    for (int cp = 0; cp < 4; ++cp){
      int c0c = cg*8 + 2*cp;
      float v0 = ((const float*)&xr[2*cp])[jj];
      float v1 = ((const float*)&xr[2*cp+1])[jj];
      aw[cp] = pack2((v0-mu)*rs*n1w[c0c] + n1b[c0c], (v1-mu)*rs*n1w[c0c+1] + n1b[c0c+1]);
      praw[jj][cp] = pack2(v0, v1);
    }
    *(uint4*)((char*)Buf1 + t*512 + ((cg*16) ^ ((t&7)<<4))) = make_uint4(aw[0],aw[1],aw[2],aw[3]);
  }
  __syncthreads();

  {
    f32x4 acc[4][2]; ZERO_ACC(acc);
    gemmF(Buf1, pkq + 65536, l, ntb, acc);
    #pragma unroll
    for (int m = 0; m < 4; ++m)
      #pragma unroll
      for (int n2 = 0; n2 < 2; ++n2)
        #pragma unroll
        for (int jj = 0; jj < 4; ++jj){
          int t = m*16 + ((l>>4)<<2) + jj;
          int c = (w<<5) + (n2<<4) + (l&15);
          *(u16*)((char*)Buf2 + t*512 + ((2*c) ^ ((t&7)<<4))) = f2bf(acc[m][n2][jj]);
        }
  }
  __syncthreads();

  const int hh = (tid >> 3) & 7, rr = tid & 7;
  const int tq = w*8 + rr;
  u32 kr[16];
  #pragma unroll
  for (int g = 0; g < 4; ++g){
    uint4 dk = *(const uint4*)((char*)Buf2 + tq*512 + ((hh*64 + 16*g) ^ ((tq&7)<<4)));
    kr[g*4+0] = dk.x; kr[g*4+1] = dk.y; kr[g*4+2] = dk.z; kr[g*4+3] = dk.w;
  }
  __syncthreads();

  {
    f32x4 acc[4][2]; ZERO_ACC(acc);
    gemmF(Buf1, pkq, l, ntb, acc);
    #pragma unroll
    for (int m = 0; m < 4; ++m)
      #pragma unroll
      for (int n2 = 0; n2 < 2; ++n2)
        #pragma unroll
        for (int jj = 0; jj < 4; ++jj){
          int t = m*16 + ((l>>4)<<2) + jj;
          int c = (w<<5) + (n2<<4) + (l&15);
          *(u16*)((char*)Buf2 + t*512 + ((2*c) ^ ((t&7)<<4))) = f2bf(acc[m][n2][jj]);
        }
  }
  __syncthreads();

  float pr[8];
  {
    float qf[32];
    #pragma unroll
    for (int g = 0; g < 4; ++g){
      uint4 dq = *(const uint4*)((char*)Buf2 + tq*512 + ((hh*64 + 16*g) ^ ((tq&7)<<4)));
      qf[g*8+0] = bf2f((u16)dq.x); qf[g*8+1] = bf2f((u16)(dq.x>>16));
      qf[g*8+2] = bf2f((u16)dq.y); qf[g*8+3] = bf2f((u16)(dq.y>>16));
      qf[g*8+4] = bf2f((u16)dq.z); qf[g*8+5] = bf2f((u16)(dq.z>>16));
      qf[g*8+6] = bf2f((u16)dq.w); qf[g*8+7] = bf2f((u16)(dq.w>>16));
    }
    float s[8];
    #pragma unroll
    for (int j = 0; j < 8; ++j){
      float dot = 0.f;
      #pragma unroll
      for (int reg = 0; reg < 16; ++reg){
        u32 kj = (u32)__shfl((int)kr[reg], j, 8);
        dot += qf[2*reg]   * bf2f((u16)kj);
        dot += qf[2*reg+1] * bf2f((u16)(kj>>16));
      }
      s[j] = dot * 0.17677669529663687f;
    }
    float mx = s[0];
    #pragma unroll
    for (int j = 1; j < 8; ++j) mx = fmaxf(mx, s[j]);
    float sum = 0.f;
    #pragma unroll
    for (int j = 0; j < 8; ++j){ pr[j] = __expf(s[j]-mx); sum += pr[j]; }
    float inv = 1.0f / sum;
    #pragma unroll
    for (int j = 0; j < 8; ++j) pr[j] *= inv;
  }
  __syncthreads();

  {
    f32x4 acc[4][2]; ZERO_ACC(acc);
    gemmF(Buf1, pkq + 131072, l, ntb, acc);
    __syncthreads();
    #pragma unroll
    for (int m = 0; m < 4; ++m)
      #pragma unroll
      for (int n2 = 0; n2 < 2; ++n2)
        #pragma unroll
        for (int jj = 0; jj < 4; ++jj){
          int t = m*16 + ((l>>4)<<2) + jj;
          int c = (w<<5) + (n2<<4) + (l&15);
          *(u16*)((char*)Buf2 + t*512 + ((2*c) ^ ((t&7)<<4))) = f2bf(acc[m][n2][jj]);
        }
    #pragma unroll
    for (int jj = 0; jj < 4; ++jj){
      int t = 4*q4 + jj;
      *(uint4*)((char*)Buf1 + t*512 + ((cg*16) ^ ((t&7)<<4))) =
          make_uint4(praw[jj][0], praw[jj][1], praw[jj][2], praw[jj][3]);
    }
  }
  __syncthreads();

  {
    u32 vr[16];
    #pragma unroll
    for (int g = 0; g < 4; ++g){
      uint4 dv = *(const uint4*)((char*)Buf2 + tq*512 + ((hh*64 + 16*g) ^ ((tq&7)<<4)));
      vr[g*4+0] = dv.x; vr[g*4+1] = dv.y; vr[g*4+2] = dv.z; vr[g*4+3] = dv.w;
    }
    float of[32];
    #pragma unroll
    for (int d = 0; d < 32; ++d) of[d] = 0.f;
    #pragma unroll
    for (int j = 0; j < 8; ++j){
      float pj = pr[j];
      #pragma unroll
      for (int reg = 0; reg < 16; ++reg){
        u32 vj = (u32)__shfl((int)vr[reg], j, 8);
        of[2*reg]   += pj*bf2f((u16)vj);
        of[2*reg+1] += pj*bf2f((u16)(vj>>16));
      }
    }
    #pragma unroll
    for (int g = 0; g < 4; ++g){
      uint4 o;
      o.x = pack2(of[g*8+0], of[g*8+1]);
      o.y = pack2(of[g*8+2], of[g*8+3]);
      o.z = pack2(of[g*8+4], of[g*8+5]);
      o.w = pack2(of[g*8+6], of[g*8+7]);
      *(uint4*)((char*)Buf2 + tq*512 + ((hh*64 + 16*g) ^ ((tq&7)<<4))) = o;
    }
  }
  __syncthreads();

  u32 xt1p[4][2][2];
  {
    f32x4 acc[4][2]; ZERO_ACC(acc);
    gemmF(Buf2, pkp, l, ntb, acc);
    __syncthreads();
    #pragma unroll
    for (int m = 0; m < 4; ++m)
      #pragma unroll
      for (int n2 = 0; n2 < 2; ++n2){
        float vv[4];
        #pragma unroll
        for (int jj = 0; jj < 4; ++jj){
          int t = m*16 + ((l>>4)<<2) + jj;
          int c = (w<<5) + (n2<<4) + (l&15);
          float rv = bf2f(*(const u16*)((char*)Buf1 + t*512 + ((2*c) ^ ((t&7)<<4))));
          float v = acc[m][n2][jj] + projb[c] + rv;
          vv[jj] = v;
          *(u16*)((char*)Buf2 + t*512 + 2*c) = f2bf(v);
        }
        xt1p[m][n2][0] = pack2(vv[0], vv[1]);
        xt1p[m][n2][1] = pack2(vv[2], vv[3]);
      }
  }
  __syncthreads();

  {
    float4 wv = *(const float4*)(n2w + 4*l);
    float4 bv = *(const float4*)(n2b + 4*l);
    #pragma unroll 1
    for (int r = 0; r < 8; ++r){
      int t = w*8 + r;
      uint2 d = *(const uint2*)((char*)Buf2 + t*512 + 8*l);
      float f0 = bf2f((u16)d.x), f1 = bf2f((u16)(d.x>>16));
      float f2 = bf2f((u16)d.y), f3 = bf2f((u16)(d.y>>16));
      float ls1 = f0+f1+f2+f3;
      float ls2 = f0*f0+f1*f1+f2*f2+f3*f3;
      #pragma unroll
      for (int off = 1; off < 64; off <<= 1){
        ls1 += __shfl_xor(ls1, off);
        ls2 += __shfl_xor(ls2, off);
      }
      float mu = ls1 * (1.f/256.f);
      float var = fmaxf(ls2 * (1.f/256.f) - mu*mu, 0.f);
      float rs = rsqrtf(var + 1e-5f);
      uint2 pp;
      pp.x = pack2((f0-mu)*rs*wv.x+bv.x, (f1-mu)*rs*wv.y+bv.y);
      pp.y = pack2((f2-mu)*rs*wv.z+bv.z, (f3-mu)*rs*wv.w+bv.w);
      *(uint2*)((char*)Buf1 + t*512 + ((8*l) ^ ((t&7)<<4))) = pp;
    }
  }
  __syncthreads();

  f32x4 acc2[4][2]; ZERO_ACC(acc2);
  #pragma unroll 1
  for (int c2 = 0; c2 < 4; ++c2){
    f32x4 acc1[4][2]; ZERO_ACC(acc1);
    gemmF(Buf1, pk1 + (size_t)c2*65536, l, ntb, acc1);
    __syncthreads();
    #pragma unroll
    for (int m = 0; m < 4; ++m)
      #pragma unroll
      for (int n2 = 0; n2 < 2; ++n2)
        #pragma unroll
        for (int jj = 0; jj < 4; ++jj){
          int t = m*16 + ((l>>4)<<2) + jj;
          int c = (w<<5) + (n2<<4) + (l&15);
          float xv = acc1[m][n2][jj] + f1b[c2*256 + c];
          float u = xv*(0.79788456f + 0.035677408f*xv*xv);
          float g = xv / (1.f + __expf(-2.f*u));
          *(u16*)((char*)Buf2 + t*512 + ((2*c) ^ ((t&7)<<4))) = f2bf(g);
        }
    __syncthreads();
    gemmF(Buf2, pk2 + (size_t)c2*65536, l, ntb, acc2);
    __syncthreads();
  }

  float* OutF = (float*)smem;
  #pragma unroll
  for (int m = 0; m < 4; ++m)
    #pragma unroll
    for (int n2 = 0; n2 < 2; ++n2)
      #pragma unroll
      for (int jj = 0; jj < 4; ++jj){
        int t = m*16 + ((l>>4)<<2) + jj;
        int c = (w<<5) + (n2<<4) + (l&15);
        u32 p = xt1p[m][n2][jj>>1];
        float rv = bf2f((u16)((jj&1) ? (p>>16) : (p&0xFFFF)));
        float v = acc2[m][n2][jj] + f2b[c] + rv;
        *(float*)((char*)OutF + c*256 + ((4*t) ^ ((c&15)<<4))) = v;
      }
  __syncthreads();

  float* ob = out + (size_t)bb*CL_;
  #pragma unroll
  for (int ii = 0; ii < 8; ++ii){
    int id = tid + ii*512;
    int c = id >> 4, qd = id & 15;
    int lw = l0 + 4*qd; if (lw >= L_) lw -= L_;
    float4 vv = *(const float4*)((char*)OutF + c*256 + ((16*qd) ^ ((c&15)<<4)));
    *(float4*)(ob + (size_t)c*L_ + lw) = vv;
  }
}

// ---------------- launch ----------------
extern "C" void kernel_launch(void* const* d_in, const int* in_sizes, int n_in,
                              void* d_out, int out_size, void* d_ws, size_t ws_size,
                              hipStream_t stream)
{
  const float* x     = (const float*)d_in[0];
  const float* n1w   = (const float*)d_in[1];
  const float* n1b   = (const float*)d_in[2];
  const float* n2w   = (const float*)d_in[3];
  const float* n2b   = (const float*)d_in[4];
  const float* qkvw  = (const float*)d_in[5];
  const float* projw = (const float*)d_in[6];
  const float* projb = (const float*)d_in[7];
  const float* f1w   = (const float*)d_in[8];
  const float* f1b   = (const float*)d_in[9];
  const float* f2w   = (const float*)d_in[10];
  const float* f2b   = (const float*)d_in[11];
  float* out = (float*)d_out;

  u16* ws  = (u16*)d_ws;
  u16* pkq = ws;                        // 3*65536 u16
  u16* pkp = pkq + 196608;              // 65536
  u16* pk1 = pkp + 65536;               // 4*65536
  u16* pk2 = pk1 + 262144;              // 262144  -> weights total 786432 u16 (1.57 MB)
  u16* xt1g = pk2 + 262144;             // 8*256*16384 u16 = 67.1 MB
  float* statsg = (float*)(xt1g + (size_t)8*CL_);   // 1.05 MB

  size_t need = (size_t)786432*2 + (size_t)8*CL_*2 + (size_t)8*16384*2*4;

  hipLaunchKernelGGL(wpack_kernel, dim3(384), dim3(256), 0, stream,
                     qkvw, projw, f1w, f2w, pkq, pkp, pk1, pk2);
  if (ws_size >= need){
    hipLaunchKernelGGL(swin_attn_kernel, dim3(2048), dim3(512), 0, stream,
                       x, n1w, n1b, pkq, pkp, projb, xt1g, statsg);
    hipLaunchKernelGGL(swin_ff_kernel, dim3(2048), dim3(512), 0, stream,
                       xt1g, statsg, n2w, n2b, pk1, f1b, pk2, f2b, out);
  } else {
    hipLaunchKernelGGL(swin_fused_kernel, dim3(2048), dim3(512), 0, stream,
                       x, n1w, n1b, n2w, n2b, pkq, pkp, projb, pk1, f1b, pk2, f2b, out);
  }
}